// Round 6
// baseline (33.211 us; speedup 1.0000x reference)
//
#include <hip/hip_runtime.h>

#define NBOX 8192
#define TOP_K 50
#define IOU_THR 0.3f
#define VAR0 0.1f
#define VAR1 0.2f
#define NT 512
#define NWAVE (NT / 64)
#define MSEL 128
#define PRE_MAX 256     // candidate capacity (C in [128,~140] expected)
#define BPT 16          // boxes per thread

#define WAITLDS() __asm__ volatile("s_waitcnt lgkmcnt(0)" ::: "memory")

__device__ __forceinline__ void decode_box(int cidx, const float* __restrict__ loc,
                                           const float* __restrict__ priors,
                                           float& x1, float& y1, float& x2, float& y2,
                                           float& area)
{
    float4 pr = *reinterpret_cast<const float4*>(priors + 4 * cidx);
    float l0 = loc[cidx * 14 + 0];
    float l1 = loc[cidx * 14 + 1];
    float l2 = loc[cidx * 14 + 2];
    float l3 = loc[cidx * 14 + 3];
    float cx = pr.x + l0 * VAR0 * pr.z;
    float cy = pr.y + l1 * VAR0 * pr.w;
    float hw = pr.z * expf(l2 * VAR0) * 0.5f;
    float hh = pr.w * expf(l3 * VAR1) * 0.5f;
    x1 = cx - hw; y1 = cy - hh; x2 = cx + hw; y2 = cy + hh;
    area = (x2 - x1) * (y2 - y1);
}

// Per-wave: bins[4*lane .. 4*lane+3] (c0..c3), higher bin = higher score.
// Finds largest bin B with suffix count >= MSEL.
__device__ __forceinline__ void find_thresh(unsigned c0, unsigned c1, unsigned c2, unsigned c3,
                                            int lane, int& bin_sel)
{
    unsigned cnt = c0 + c1 + c2 + c3;
    unsigned S = cnt;                       // suffix sum over lanes >= lane
    #pragma unroll
    for (int d = 1; d < 64; d <<= 1) {
        unsigned t = __shfl_down(S, d);
        if (lane + d < 64) S += t;
    }
    unsigned long long bal = __ballot(S >= MSEL);
    int lstar = 63 - __clzll(bal);
    int src = (lstar < 63) ? (lstar + 1) : lstar;
    unsigned Snext = __shfl(S, src);
    unsigned above = (lstar < 63) ? Snext : 0u;
    unsigned bl[4] = {c0, c1, c2, c3};
    int bsel = -1; unsigned acc = above;
    #pragma unroll
    for (int k = 3; k >= 0; --k) {
        if (bsel < 0) {
            if (acc + bl[k] >= MSEL) bsel = k;
            else acc += bl[k];
        }
    }
    bin_sel = 4 * lstar + __shfl(bsel, lstar);
}

// ---- wave-0-only fallback machinery (exact; never taken on this data) ----
__device__ void bitonic_sort_w0(unsigned long long* a, int S, int lane)
{
    for (int k = 2; k <= S; k <<= 1) {
        for (int j = k >> 1; j > 0; j >>= 1) {
            WAITLDS();
            for (int i = lane; i < S; i += 64) {
                int l = i ^ j;
                if (l > i) {
                    unsigned long long A = a[i];
                    unsigned long long B = a[l];
                    bool asc = ((i & k) == 0);
                    if ((A > B) == asc) { a[i] = B; a[l] = A; }
                }
            }
        }
    }
    WAITLDS();
}

__device__ void greedy_nms_serial(const unsigned long long* __restrict__ arr, int n, int lane,
                                  const float* __restrict__ loc, const float* __restrict__ priors,
                                  int* keep_out)
{
    float kx1 = 0.f, ky1 = 0.f, kx2 = 0.f, ky2 = 0.f, karea = 0.f;
    int my_keep = 0, idx0 = 0, kept = 0;
    bool done = false;
    for (int p = 0; p < n && !done; p += 64) {
        int cidx = 0;
        float x1 = 0.f, y1 = 0.f, x2 = 0.f, y2 = 0.f, area = 0.f;
        int pos = p + lane;
        if (pos < n) {
            cidx = (int)(arr[pos] & 0xFFFFFFFFull);
            decode_box(cidx, loc, priors, x1, y1, x2, y2, area);
        }
        int nb = (n - p) < 64 ? (n - p) : 64;
        for (int c = 0; c < nb; ++c) {
            float bx1 = __shfl(x1, c);
            float by1 = __shfl(y1, c);
            float bx2 = __shfl(x2, c);
            float by2 = __shfl(y2, c);
            float barea = __shfl(area, c);
            int   bidx  = __shfl(cidx, c);
            float iw = fmaxf(fminf(kx2, bx2) - fmaxf(kx1, bx1), 0.0f);
            float ih = fmaxf(fminf(ky2, by2) - fmaxf(ky1, by1), 0.0f);
            float inter = iw * ih;
            float v = inter / (karea + barea - inter);
            bool sup = (lane < kept) && (v > IOU_THR);
            if (__ballot(sup) == 0ull) {
                if (kept == 0) idx0 = bidx;
                if (lane == kept) {
                    kx1 = bx1; ky1 = by1; kx2 = bx2; ky2 = by2; karea = barea;
                    my_keep = bidx;
                }
                ++kept;
                if (kept == TOP_K) { done = true; break; }
            }
        }
    }
    if (lane < TOP_K) keep_out[lane] = (lane < kept) ? my_keep : idx0;
}

__global__ __launch_bounds__(NT) void yunet_fused_kernel(
    const float* __restrict__ loc,    // [NBOX][14]
    const float* __restrict__ conf,   // [NBOX][2]
    const float* __restrict__ iou,    // [NBOX][1]
    const float* __restrict__ priors, // [NBOX][4]
    float* __restrict__ out)          // [TOP_K][15]
{
    __shared__ unsigned long long keys[NBOX];     // fallback space; main: sorted cand keys
    __shared__ unsigned long long cand[PRE_MAX];
    __shared__ unsigned hist[NWAVE][256] __attribute__((aligned(16)));
    __shared__ float4 boxs4[PRE_MAX];             // decoded boxes, sorted order
    __shared__ float  boxsa[PRE_MAX];
    __shared__ float4 keptb4[TOP_K];
    __shared__ float  kepta[TOP_K];
    __shared__ int keep_sh[TOP_K];
    __shared__ unsigned sh_cnt;

    const int tid  = threadIdx.x;
    const int lane = tid & 63;
    const int wid  = tid >> 6;

    // ---- issue all global loads first ----
    const float4* conf4 = reinterpret_cast<const float4*>(conf);
    const float4* iou4  = reinterpret_cast<const float4*>(iou);
    float4 cf[8], io[4];
    #pragma unroll
    for (int m = 0; m < 2; ++m)
        #pragma unroll
        for (int q = 0; q < 4; ++q)
            cf[m * 4 + q] = conf4[(m * NT + tid) * 4 + q];
    #pragma unroll
    for (int m = 0; m < 2; ++m)
        #pragma unroll
        for (int r = 0; r < 2; ++r)
            io[m * 2 + r] = iou4[(m * NT + tid) * 2 + r];

    // ---- zero own histogram copy (wave-private: no barrier needed) ----
    #pragma unroll
    for (int i = 0; i < 4; ++i) hist[wid][lane + 64 * i] = 0;
    if (tid == 0) sh_cnt = 0;
    WAITLDS();

    // ---- Phase 1: scores (registers) + per-wave linear-bin histogram ----
    unsigned sbv[BPT];
    #pragma unroll
    for (int m = 0; m < 2; ++m) {
        float sc[8], uu[8];
        #pragma unroll
        for (int q = 0; q < 4; ++q) {
            sc[2 * q]     = cf[m * 4 + q].y;
            sc[2 * q + 1] = cf[m * 4 + q].w;
        }
        #pragma unroll
        for (int r = 0; r < 2; ++r) {
            uu[4 * r + 0] = io[m * 2 + r].x; uu[4 * r + 1] = io[m * 2 + r].y;
            uu[4 * r + 2] = io[m * 2 + r].z; uu[4 * r + 3] = io[m * 2 + r].w;
        }
        #pragma unroll
        for (int q = 0; q < 8; ++q) {
            float u = fminf(fmaxf(uu[q], 0.0f), 1.0f);
            float s = sqrtf(sc[q] * u);
            unsigned sb = __float_as_uint(s);   // s >= 0 -> monotonic bits
            sbv[m * 8 + q] = sb;
            int bin = (int)(s * 256.0f); bin = bin > 255 ? 255 : bin;
            atomicAdd(&hist[wid][bin], 1u);
        }
    }
    __syncthreads();                              // barrier 1 of 2

    // ---- Phase 2: threshold bin B (wave-redundant, deterministic) ----
    int B;
    {
        unsigned c0 = 0, c1 = 0, c2 = 0, c3 = 0;
        #pragma unroll
        for (int w = 0; w < NWAVE; ++w) {
            uint4 h = *(const uint4*)&hist[w][4 * lane];
            c0 += h.x; c1 += h.y; c2 += h.z; c3 += h.w;
        }
        find_thresh(c0, c1, c2, c3, lane, B);
    }

    // ---- Phase 3: compact (one aggregated atomic per wave per q-step) ----
    #pragma unroll
    for (int m = 0; m < 2; ++m) {
        #pragma unroll
        for (int q = 0; q < 8; ++q) {
            unsigned sb = sbv[m * 8 + q];
            float s = __uint_as_float(sb);
            int bin = (int)(s * 256.0f); bin = bin > 255 ? 255 : bin;
            bool pred = (bin >= B);
            unsigned long long bal = __ballot(pred);
            if (pred) {
                int myoff = __popcll(bal & ((1ull << lane) - 1ull));
                unsigned base = 0;
                if (myoff == 0) base = atomicAdd(&sh_cnt, (unsigned)__popcll(bal));
                base = (unsigned)__builtin_amdgcn_readfirstlane((int)base);
                unsigned pos = base + (unsigned)myoff;
                if (pos < PRE_MAX)
                    cand[pos] = ((unsigned long long)(~sb) << 32)
                              | (unsigned)((m * NT + tid) * 8 + q);
            }
        }
    }
    __syncthreads();                              // barrier 2 of 2
    const int C = (int)sh_cnt;

    if (wid != 0) return;                         // waves 1-7 done

    // ======== wave 0 only from here (no __syncthreads below) ========
    bool need_fallback = (C > PRE_MAX);

    if (!need_fallback) {
        // ---- Phase 4: rank sort (exact; keys unique) + parallel box decode ----
        for (int i = lane; i < C; i += 64) {
            unsigned long long k = cand[i];
            int r = 0, j = 0;
            for (; j + 4 <= C; j += 4) {
                r += (cand[j]     < k) ? 1 : 0;
                r += (cand[j + 1] < k) ? 1 : 0;
                r += (cand[j + 2] < k) ? 1 : 0;
                r += (cand[j + 3] < k) ? 1 : 0;
            }
            for (; j < C; ++j) r += (cand[j] < k) ? 1 : 0;
            int cidx = (int)(k & 0xFFFFFFFFull);
            float x1, y1, x2, y2, area;
            decode_box(cidx, loc, priors, x1, y1, x2, y2, area);
            keys[r] = k;
            boxs4[r] = make_float4(x1, y1, x2, y2);
            boxsa[r] = area;
        }
        WAITLDS();

        // ---- Phase 5: batch NMS, scalar recurrence via readlane ----
        int kept = 0;
        for (int p = 0; p < C && kept < TOP_K; p += 64) {
            int pos = p + lane;
            bool valid = pos < C;
            int rp = valid ? pos : 0;
            float4 b = boxs4[rp]; float a = boxsa[rp];

            // vs previously-kept boxes (uniform trip count)
            bool supP = !valid;
            for (int j = 0; j < kept; ++j) {
                float4 kb = keptb4[j]; float ka = kepta[j];
                float iw = fmaxf(fminf(b.z, kb.z) - fmaxf(b.x, kb.x), 0.f);
                float ih = fmaxf(fminf(b.w, kb.w) - fmaxf(b.y, kb.y), 0.f);
                float inter = iw * ih;
                supP = supP || (inter > IOU_THR * (a + ka - inter));
            }
            unsigned long long sup_prev = __ballot(supP);

            // row of the 64x64 IoU matrix (lane = row), cols via LDS broadcast
            unsigned mlo = 0u, mhi = 0u;
            for (int j = 0; j < 64; ++j) {
                int cp = (p + j < C) ? p + j : 0;
                float4 cb = boxs4[cp]; float ca = boxsa[cp];
                float iw = fmaxf(fminf(b.z, cb.z) - fmaxf(b.x, cb.x), 0.f);
                float ih = fmaxf(fminf(b.w, cb.w) - fmaxf(b.y, cb.y), 0.f);
                float inter = iw * ih;
                unsigned bit = (inter > IOU_THR * (a + ca - inter)) ? 1u : 0u;
                if (j < 32) mlo |= bit << j; else mhi |= bit << (j - 32);
            }

            // exact greedy recurrence — fully scalar (readlane, SALU)
            unsigned long long keepcur = 0ull;
            int kept0 = kept;
            for (int j = 0; j < 64 && kept < TOP_K; ++j) {
                if (!((sup_prev >> j) & 1ull)) {
                    unsigned long long mj =
                        ((unsigned long long)(unsigned)__builtin_amdgcn_readlane((int)mhi, j) << 32)
                      | (unsigned)__builtin_amdgcn_readlane((int)mlo, j);
                    unsigned long long lower = (1ull << j) - 1ull;
                    if (!(mj & keepcur & lower)) { keepcur |= (1ull << j); ++kept; }
                }
            }

            unsigned long long lowm = (1ull << lane) - 1ull;
            if ((keepcur >> lane) & 1ull) {
                int rank = kept0 + __popcll(keepcur & lowm);
                keep_sh[rank] = (int)(keys[pos] & 0xFFFFFFFFull);
                keptb4[rank] = b;
                kepta[rank] = a;
            }
            WAITLDS();
        }
        need_fallback = (kept < TOP_K);
    }

    // ---- Fallback: wave-0-only exact full path (never taken on this data) ----
    if (need_fallback) {
        for (int i = lane; i < NBOX; i += 64) {
            float c = conf[2 * i + 1];
            float u = fminf(fmaxf(iou[i], 0.f), 1.f);
            float s = sqrtf(c * u);
            keys[i] = ((unsigned long long)(~__float_as_uint(s)) << 32) | (unsigned)i;
        }
        bitonic_sort_w0(keys, NBOX, lane);
        greedy_nms_serial(keys, NBOX, lane, loc, priors, keep_sh);
        WAITLDS();
    }

    // ---- Phase 6: output rows (lanes 0..49) ----
    if (lane < TOP_K) {
        int i = keep_sh[lane];
        float4 pr = *reinterpret_cast<const float4*>(priors + 4 * i);
        float cx = pr.x + loc[i * 14 + 0] * VAR0 * pr.z;
        float cy = pr.y + loc[i * 14 + 1] * VAR0 * pr.w;
        float hw = pr.z * expf(loc[i * 14 + 2] * VAR0) * 0.5f;
        float hh = pr.w * expf(loc[i * 14 + 3] * VAR1) * 0.5f;
        float* o = out + lane * 15;
        o[0] = cx - hw;
        o[1] = cy - hh;
        o[2] = cx + hw;
        o[3] = cy + hh;
        #pragma unroll
        for (int q = 0; q < 5; ++q) {
            o[4 + 2 * q] = pr.x + loc[i * 14 + 4 + 2 * q] * VAR0 * pr.z;
            o[5 + 2 * q] = pr.y + loc[i * 14 + 5 + 2 * q] * VAR0 * pr.w;
        }
        float cc = conf[i * 2 + 1];
        float u  = fminf(fmaxf(iou[i], 0.0f), 1.0f);
        o[14] = sqrtf(cc * u);
    }
}

extern "C" void kernel_launch(void* const* d_in, const int* in_sizes, int n_in,
                              void* d_out, int out_size, void* d_ws, size_t ws_size,
                              hipStream_t stream) {
    const float* loc    = (const float*)d_in[0];
    const float* conf   = (const float*)d_in[1];
    const float* iou    = (const float*)d_in[2];
    const float* priors = (const float*)d_in[3];
    float* out = (float*)d_out;

    yunet_fused_kernel<<<1, NT, 0, stream>>>(loc, conf, iou, priors, out);
}

// Round 7
// 23.596 us; speedup vs baseline: 1.4075x; 1.4075x over previous
//
#include <hip/hip_runtime.h>

#define NBOX 8192
#define TOP_K 50
#define IOU_THR 0.3f
#define VAR0 0.1f
#define VAR1 0.2f
#define NT 512
#define NWAVE (NT / 64)
#define MSEL 128
#define PRE_MAX 256     // candidate capacity (C in [128,~140] expected)
#define BPT 16          // boxes per thread

__device__ __forceinline__ void decode_box(int cidx, const float* __restrict__ loc,
                                           const float* __restrict__ priors,
                                           float& x1, float& y1, float& x2, float& y2,
                                           float& area)
{
    float4 pr = *reinterpret_cast<const float4*>(priors + 4 * cidx);
    float l0 = loc[cidx * 14 + 0];
    float l1 = loc[cidx * 14 + 1];
    float l2 = loc[cidx * 14 + 2];
    float l3 = loc[cidx * 14 + 3];
    float cx = pr.x + l0 * VAR0 * pr.z;
    float cy = pr.y + l1 * VAR0 * pr.w;
    float hw = pr.z * expf(l2 * VAR0) * 0.5f;
    float hh = pr.w * expf(l3 * VAR1) * 0.5f;
    x1 = cx - hw; y1 = cy - hh; x2 = cx + hw; y2 = cy + hh;
    area = (x2 - x1) * (y2 - y1);
}

// Per-wave: bins[4*lane .. 4*lane+3] (c0..c3), higher bin = higher score.
// Finds largest bin B with suffix count >= MSEL.
__device__ __forceinline__ void find_thresh(unsigned c0, unsigned c1, unsigned c2, unsigned c3,
                                            int lane, int& bin_sel)
{
    unsigned cnt = c0 + c1 + c2 + c3;
    unsigned S = cnt;                       // suffix sum over lanes >= lane
    #pragma unroll
    for (int d = 1; d < 64; d <<= 1) {
        unsigned t = __shfl_down(S, d);
        if (lane + d < 64) S += t;
    }
    unsigned long long bal = __ballot(S >= MSEL);
    int lstar = 63 - __clzll(bal);
    int src = (lstar < 63) ? (lstar + 1) : lstar;
    unsigned Snext = __shfl(S, src);
    unsigned above = (lstar < 63) ? Snext : 0u;
    unsigned bl[4] = {c0, c1, c2, c3};
    int bsel = -1; unsigned acc = above;
    #pragma unroll
    for (int k = 3; k >= 0; --k) {
        if (bsel < 0) {
            if (acc + bl[k] >= MSEL) bsel = k;
            else acc += bl[k];
        }
    }
    bin_sel = 4 * lstar + __shfl(bsel, lstar);
}

// ---- fallback machinery (exact; never taken on this data) ----
__device__ void bitonic_sort(unsigned long long* a, int S, int tid)
{
    for (int k = 2; k <= S; k <<= 1) {
        for (int j = k >> 1; j > 0; j >>= 1) {
            __syncthreads();
            for (int i = tid; i < S; i += NT) {
                int l = i ^ j;
                if (l > i) {
                    unsigned long long A = a[i];
                    unsigned long long B = a[l];
                    bool asc = ((i & k) == 0);
                    if ((A > B) == asc) { a[i] = B; a[l] = A; }
                }
            }
        }
    }
    __syncthreads();
}

__device__ void greedy_nms_serial(const unsigned long long* __restrict__ arr, int n, int lane,
                                  const float* __restrict__ loc, const float* __restrict__ priors,
                                  int* keep_out)
{
    float kx1 = 0.f, ky1 = 0.f, kx2 = 0.f, ky2 = 0.f, karea = 0.f;
    int my_keep = 0, idx0 = 0, kept = 0;
    bool done = false;
    for (int p = 0; p < n && !done; p += 64) {
        int cidx = 0;
        float x1 = 0.f, y1 = 0.f, x2 = 0.f, y2 = 0.f, area = 0.f;
        int pos = p + lane;
        if (pos < n) {
            cidx = (int)(arr[pos] & 0xFFFFFFFFull);
            decode_box(cidx, loc, priors, x1, y1, x2, y2, area);
        }
        int nb = (n - p) < 64 ? (n - p) : 64;
        for (int c = 0; c < nb; ++c) {
            float bx1 = __shfl(x1, c);
            float by1 = __shfl(y1, c);
            float bx2 = __shfl(x2, c);
            float by2 = __shfl(y2, c);
            float barea = __shfl(area, c);
            int   bidx  = __shfl(cidx, c);
            float iw = fmaxf(fminf(kx2, bx2) - fmaxf(kx1, bx1), 0.0f);
            float ih = fmaxf(fminf(ky2, by2) - fmaxf(ky1, by1), 0.0f);
            float inter = iw * ih;
            float v = inter / (karea + barea - inter);
            bool sup = (lane < kept) && (v > IOU_THR);
            if (__ballot(sup) == 0ull) {
                if (kept == 0) idx0 = bidx;
                if (lane == kept) {
                    kx1 = bx1; ky1 = by1; kx2 = bx2; ky2 = by2; karea = barea;
                    my_keep = bidx;
                }
                ++kept;
                if (kept == TOP_K) { done = true; break; }
            }
        }
    }
    if (lane < TOP_K) keep_out[lane] = (lane < kept) ? my_keep : idx0;
}

__global__ __launch_bounds__(NT) void yunet_fused_kernel(
    const float* __restrict__ loc,    // [NBOX][14]
    const float* __restrict__ conf,   // [NBOX][2]
    const float* __restrict__ iou,    // [NBOX][1]
    const float* __restrict__ priors, // [NBOX][4]
    float* __restrict__ out)          // [TOP_K][15]
{
    __shared__ unsigned long long keys[NBOX];     // fallback only
    __shared__ unsigned long long cand[PRE_MAX];
    __shared__ unsigned hist[NWAVE][256] __attribute__((aligned(16)));
    __shared__ unsigned long long maskbuf[64];
    __shared__ unsigned long long sh_supprev;
    __shared__ float4 boxs4[PRE_MAX];             // decoded boxes, sorted order
    __shared__ float  boxsa[PRE_MAX];
    __shared__ int    idxs[PRE_MAX];              // original index, sorted order
    __shared__ float4 keptb4[TOP_K];
    __shared__ float  kepta[TOP_K];
    __shared__ int keep_sh[TOP_K];
    __shared__ unsigned sh_cnt;
    __shared__ int sh_flag, sh_kept;

    const int tid  = threadIdx.x;
    const int lane = tid & 63;
    const int wid  = tid >> 6;

    // ---- issue all global loads first ----
    const float4* conf4 = reinterpret_cast<const float4*>(conf);
    const float4* iou4  = reinterpret_cast<const float4*>(iou);
    float4 cf[8], io[4];
    #pragma unroll
    for (int m = 0; m < 2; ++m)
        #pragma unroll
        for (int q = 0; q < 4; ++q)
            cf[m * 4 + q] = conf4[(m * NT + tid) * 4 + q];
    #pragma unroll
    for (int m = 0; m < 2; ++m)
        #pragma unroll
        for (int r = 0; r < 2; ++r)
            io[m * 2 + r] = iou4[(m * NT + tid) * 2 + r];

    // ---- zero own histogram copy (wave-private) ----
    #pragma unroll
    for (int i = 0; i < 4; ++i) hist[wid][lane + 64 * i] = 0;
    if (tid == 0) { sh_cnt = 0; sh_flag = 0; sh_kept = 0; }
    __asm__ volatile("s_waitcnt lgkmcnt(0)" ::: "memory");

    // ---- Phase 1: scores (registers) + per-wave linear-bin histogram ----
    unsigned sbv[BPT];
    #pragma unroll
    for (int m = 0; m < 2; ++m) {
        float sc[8], uu[8];
        #pragma unroll
        for (int q = 0; q < 4; ++q) {
            sc[2 * q]     = cf[m * 4 + q].y;
            sc[2 * q + 1] = cf[m * 4 + q].w;
        }
        #pragma unroll
        for (int r = 0; r < 2; ++r) {
            uu[4 * r + 0] = io[m * 2 + r].x; uu[4 * r + 1] = io[m * 2 + r].y;
            uu[4 * r + 2] = io[m * 2 + r].z; uu[4 * r + 3] = io[m * 2 + r].w;
        }
        #pragma unroll
        for (int q = 0; q < 8; ++q) {
            float u = fminf(fmaxf(uu[q], 0.0f), 1.0f);
            float s = sqrtf(sc[q] * u);
            unsigned sb = __float_as_uint(s);   // s >= 0 -> monotonic bits
            sbv[m * 8 + q] = sb;
            int bin = (int)(s * 256.0f); bin = bin > 255 ? 255 : bin;
            atomicAdd(&hist[wid][bin], 1u);
        }
    }
    __syncthreads();                              // B1

    // ---- Phase 2: threshold bin B (wave-redundant, deterministic) ----
    int B;
    {
        unsigned c0 = 0, c1 = 0, c2 = 0, c3 = 0;
        #pragma unroll
        for (int w = 0; w < NWAVE; ++w) {
            uint4 h = *(const uint4*)&hist[w][4 * lane];
            c0 += h.x; c1 += h.y; c2 += h.z; c3 += h.w;
        }
        find_thresh(c0, c1, c2, c3, lane, B);
    }

    // ---- Phase 3: compact (one aggregated atomic per wave per q-step) ----
    #pragma unroll
    for (int m = 0; m < 2; ++m) {
        #pragma unroll
        for (int q = 0; q < 8; ++q) {
            unsigned sb = sbv[m * 8 + q];
            float s = __uint_as_float(sb);
            int bin = (int)(s * 256.0f); bin = bin > 255 ? 255 : bin;
            bool pred = (bin >= B);
            unsigned long long bal = __ballot(pred);
            if (pred) {
                int myoff = __popcll(bal & ((1ull << lane) - 1ull));
                unsigned base = 0;
                if (myoff == 0) base = atomicAdd(&sh_cnt, (unsigned)__popcll(bal));
                base = (unsigned)__builtin_amdgcn_readfirstlane((int)base);
                unsigned pos = base + (unsigned)myoff;
                if (pos < PRE_MAX)
                    cand[pos] = ((unsigned long long)(~sb) << 32)
                              | (unsigned)((m * NT + tid) * 8 + q);
            }
        }
    }
    __syncthreads();                              // B2
    const int C = (int)sh_cnt;

    if (C <= PRE_MAX) {
        // ---- Phase 4: rank sort (exact; keys unique) + parallel box decode ----
        if (tid < C) {
            unsigned long long k = cand[tid];
            int r = 0, j = 0;
            for (; j + 4 <= C; j += 4) {
                r += (cand[j]     < k) ? 1 : 0;
                r += (cand[j + 1] < k) ? 1 : 0;
                r += (cand[j + 2] < k) ? 1 : 0;
                r += (cand[j + 3] < k) ? 1 : 0;
            }
            for (; j < C; ++j) r += (cand[j] < k) ? 1 : 0;
            int cidx = (int)(k & 0xFFFFFFFFull);
            float x1, y1, x2, y2, area;
            decode_box(cidx, loc, priors, x1, y1, x2, y2, area);
            boxs4[r] = make_float4(x1, y1, x2, y2);
            boxsa[r] = area;
            idxs[r] = cidx;
        }
        __syncthreads();                          // B3

        // ---- Phase 5: batch-mask greedy NMS (2 barriers per batch) ----
        for (int p = 0; p < C; p += 64) {
            // stage A (wave 0): batch vs previously-kept boxes — same interval as B
            if (tid < 64) {
                int pos = p + lane;
                bool valid = pos < C;
                int rp = valid ? pos : 0;
                float4 b = boxs4[rp]; float a = boxsa[rp];
                int kept = sh_kept;
                bool supP = !valid;
                for (int j = 0; j < kept; ++j) {
                    float4 kb = keptb4[j]; float ka = kepta[j];
                    float iw = fmaxf(fminf(b.z, kb.z) - fmaxf(b.x, kb.x), 0.f);
                    float ih = fmaxf(fminf(b.w, kb.w) - fmaxf(b.y, kb.y), 0.f);
                    float inter = iw * ih;
                    supP = supP || (inter > IOU_THR * (a + ka - inter));
                }
                unsigned long long sp = __ballot(supP);
                if (lane == 0) sh_supprev = sp;
            }
            // stage B (all 512 threads): 64x64 IoU bit-matrix, 8 pairs each
            {
                int r  = tid >> 3;
                int cb = tid & 7;
                int rp = (p + r < C) ? p + r : 0;
                float4 rb = boxs4[rp]; float ra = boxsa[rp];
                unsigned byte = 0;
                #pragma unroll
                for (int k = 0; k < 8; ++k) {
                    int c = cb * 8 + k;
                    int cp = (p + c < C) ? p + c : 0;
                    float4 cx = boxs4[cp]; float ca = boxsa[cp];
                    float iw = fmaxf(fminf(rb.z, cx.z) - fmaxf(rb.x, cx.x), 0.f);
                    float ih = fmaxf(fminf(rb.w, cx.w) - fmaxf(rb.y, cx.y), 0.f);
                    float inter = iw * ih;
                    byte |= (unsigned)((inter > IOU_THR * (ra + ca - inter)) ? 1u : 0u) << k;
                }
                ((unsigned char*)maskbuf)[tid] = (unsigned char)byte;
            }
            __syncthreads();                      // B4 (per batch)

            // stage C (wave 0): exact greedy recurrence via shfl broadcast
            if (tid < 64) {
                unsigned long long mymask = maskbuf[lane];
                unsigned long long sup_prev = sh_supprev;
                unsigned long long keepcur = 0ull;
                const int kept0 = sh_kept;
                int kept = kept0;
                for (int i2 = 0; i2 < 64 && kept < TOP_K; ++i2) {
                    unsigned long long mi = __shfl(mymask, i2);
                    unsigned long long lower = (1ull << i2) - 1ull;
                    if (!((sup_prev >> i2) & 1ull) && !(mi & keepcur & lower)) {
                        keepcur |= 1ull << i2;
                        ++kept;
                    }
                }
                unsigned long long lowm = (1ull << lane) - 1ull;
                int rank = kept0 + __popcll(keepcur & lowm);
                if (((keepcur >> lane) & 1ull) && rank < TOP_K) {
                    int pos = p + lane;
                    keep_sh[rank] = idxs[pos];
                    keptb4[rank] = boxs4[pos];
                    kepta[rank] = boxsa[pos];
                }
                if (lane == 0) sh_kept = kept;
            }
            __syncthreads();                      // B5 (per batch)
            if (sh_kept >= TOP_K) break;
        }
        if (tid == 0) sh_flag = (sh_kept >= TOP_K) ? 0 : 1;
    } else {
        if (tid == 0) sh_flag = 1;
    }
    __syncthreads();                              // B6

    // ---- Fallback: exact full path (never taken on this data) ----
    if (sh_flag) {
        #pragma unroll
        for (int m = 0; m < 2; ++m) {
            #pragma unroll
            for (int q = 0; q < 8; ++q) {
                int i = (m * NT + tid) * 8 + q;
                keys[i] = ((unsigned long long)(~sbv[m * 8 + q]) << 32) | (unsigned)i;
            }
        }
        __syncthreads();
        bitonic_sort(keys, NBOX, tid);
        if (tid < 64) greedy_nms_serial(keys, NBOX, tid, loc, priors, keep_sh);
        if (tid == 0) sh_kept = TOP_K;   // serial path fills all TOP_K slots
        __syncthreads();
    }

    // ---- Phase 6: output rows (tid 0..49 = wave 0; no extra barrier) ----
    if (tid < TOP_K) {
        int src = (tid < sh_kept) ? tid : 0;   // fill = first kept index
        int i = keep_sh[src];
        float4 pr = *reinterpret_cast<const float4*>(priors + 4 * i);
        float cx = pr.x + loc[i * 14 + 0] * VAR0 * pr.z;
        float cy = pr.y + loc[i * 14 + 1] * VAR0 * pr.w;
        float hw = pr.z * expf(loc[i * 14 + 2] * VAR0) * 0.5f;
        float hh = pr.w * expf(loc[i * 14 + 3] * VAR1) * 0.5f;
        float* o = out + tid * 15;
        o[0] = cx - hw;
        o[1] = cy - hh;
        o[2] = cx + hw;
        o[3] = cy + hh;
        #pragma unroll
        for (int q = 0; q < 5; ++q) {
            o[4 + 2 * q] = pr.x + loc[i * 14 + 4 + 2 * q] * VAR0 * pr.z;
            o[5 + 2 * q] = pr.y + loc[i * 14 + 5 + 2 * q] * VAR0 * pr.w;
        }
        float cc = conf[i * 2 + 1];
        float u  = fminf(fmaxf(iou[i], 0.0f), 1.0f);
        o[14] = sqrtf(cc * u);
    }
}

extern "C" void kernel_launch(void* const* d_in, const int* in_sizes, int n_in,
                              void* d_out, int out_size, void* d_ws, size_t ws_size,
                              hipStream_t stream) {
    const float* loc    = (const float*)d_in[0];
    const float* conf   = (const float*)d_in[1];
    const float* iou    = (const float*)d_in[2];
    const float* priors = (const float*)d_in[3];
    float* out = (float*)d_out;

    yunet_fused_kernel<<<1, NT, 0, stream>>>(loc, conf, iou, priors, out);
}

// Round 8
// 22.712 us; speedup vs baseline: 1.4622x; 1.0389x over previous
//
#include <hip/hip_runtime.h>

#define NBOX 8192
#define TOP_K 50
#define IOU_THR 0.3f
#define VAR0 0.1f
#define VAR1 0.2f
#define NT 512
#define NWAVE (NT / 64)
#define MSEL_SUB 32     // target suffix count in the 1/4-subsampled histogram
#define PRE_MAX 256     // candidate capacity (E[C]~128)
#define BPT 16          // boxes per thread

__device__ __forceinline__ void decode_box(int cidx, const float* __restrict__ loc,
                                           const float* __restrict__ priors,
                                           float& x1, float& y1, float& x2, float& y2,
                                           float& area)
{
    float4 pr = *reinterpret_cast<const float4*>(priors + 4 * cidx);
    float l0 = loc[cidx * 14 + 0];
    float l1 = loc[cidx * 14 + 1];
    float l2 = loc[cidx * 14 + 2];
    float l3 = loc[cidx * 14 + 3];
    float cx = pr.x + l0 * VAR0 * pr.z;
    float cy = pr.y + l1 * VAR0 * pr.w;
    float hw = pr.z * expf(l2 * VAR0) * 0.5f;
    float hh = pr.w * expf(l3 * VAR1) * 0.5f;
    x1 = cx - hw; y1 = cy - hh; x2 = cx + hw; y2 = cy + hh;
    area = (x2 - x1) * (y2 - y1);
}

// Per-wave: bins[4*lane .. 4*lane+3] (c0..c3), higher bin = higher score.
// Finds largest bin B whose suffix count >= target.
__device__ __forceinline__ void find_thresh(unsigned c0, unsigned c1, unsigned c2, unsigned c3,
                                            int lane, unsigned target, int& bin_sel)
{
    unsigned cnt = c0 + c1 + c2 + c3;
    unsigned S = cnt;                       // suffix sum over lanes >= lane
    #pragma unroll
    for (int d = 1; d < 64; d <<= 1) {
        unsigned t = __shfl_down(S, d);
        if (lane + d < 64) S += t;
    }
    unsigned long long bal = __ballot(S >= target);
    int lstar = 63 - __clzll(bal);
    int src = (lstar < 63) ? (lstar + 1) : lstar;
    unsigned Snext = __shfl(S, src);
    unsigned above = (lstar < 63) ? Snext : 0u;
    unsigned bl[4] = {c0, c1, c2, c3};
    int bsel = -1; unsigned acc = above;
    #pragma unroll
    for (int k = 3; k >= 0; --k) {
        if (bsel < 0) {
            if (acc + bl[k] >= target) bsel = k;
            else acc += bl[k];
        }
    }
    bin_sel = 4 * lstar + __shfl(bsel, lstar);
}

// ---- fallback machinery (exact; never taken on this data) ----
__device__ void bitonic_sort(unsigned long long* a, int S, int tid)
{
    for (int k = 2; k <= S; k <<= 1) {
        for (int j = k >> 1; j > 0; j >>= 1) {
            __syncthreads();
            for (int i = tid; i < S; i += NT) {
                int l = i ^ j;
                if (l > i) {
                    unsigned long long A = a[i];
                    unsigned long long B = a[l];
                    bool asc = ((i & k) == 0);
                    if ((A > B) == asc) { a[i] = B; a[l] = A; }
                }
            }
        }
    }
    __syncthreads();
}

__device__ void greedy_nms_serial(const unsigned long long* __restrict__ arr, int n, int lane,
                                  const float* __restrict__ loc, const float* __restrict__ priors,
                                  int* keep_out)
{
    float kx1 = 0.f, ky1 = 0.f, kx2 = 0.f, ky2 = 0.f, karea = 0.f;
    int my_keep = 0, idx0 = 0, kept = 0;
    bool done = false;
    for (int p = 0; p < n && !done; p += 64) {
        int cidx = 0;
        float x1 = 0.f, y1 = 0.f, x2 = 0.f, y2 = 0.f, area = 0.f;
        int pos = p + lane;
        if (pos < n) {
            cidx = (int)(arr[pos] & 0xFFFFFFFFull);
            decode_box(cidx, loc, priors, x1, y1, x2, y2, area);
        }
        int nb = (n - p) < 64 ? (n - p) : 64;
        for (int c = 0; c < nb; ++c) {
            float bx1 = __shfl(x1, c);
            float by1 = __shfl(y1, c);
            float bx2 = __shfl(x2, c);
            float by2 = __shfl(y2, c);
            float barea = __shfl(area, c);
            int   bidx  = __shfl(cidx, c);
            float iw = fmaxf(fminf(kx2, bx2) - fmaxf(kx1, bx1), 0.0f);
            float ih = fmaxf(fminf(ky2, by2) - fmaxf(ky1, by1), 0.0f);
            float inter = iw * ih;
            float v = inter / (karea + barea - inter);
            bool sup = (lane < kept) && (v > IOU_THR);
            if (__ballot(sup) == 0ull) {
                if (kept == 0) idx0 = bidx;
                if (lane == kept) {
                    kx1 = bx1; ky1 = by1; kx2 = bx2; ky2 = by2; karea = barea;
                    my_keep = bidx;
                }
                ++kept;
                if (kept == TOP_K) { done = true; break; }
            }
        }
    }
    if (lane < TOP_K) keep_out[lane] = (lane < kept) ? my_keep : idx0;
}

__global__ __launch_bounds__(NT) void yunet_fused_kernel(
    const float* __restrict__ loc,    // [NBOX][14]
    const float* __restrict__ conf,   // [NBOX][2]
    const float* __restrict__ iou,    // [NBOX][1]
    const float* __restrict__ priors, // [NBOX][4]
    float* __restrict__ out)          // [TOP_K][15]
{
    __shared__ unsigned long long keys[NBOX];     // fallback only
    __shared__ unsigned long long cand[PRE_MAX];
    __shared__ unsigned hist[NWAVE][256] __attribute__((aligned(16)));
    __shared__ unsigned long long maskbuf[64];
    __shared__ float4 boxs4[PRE_MAX];             // decoded boxes, sorted order
    __shared__ float  boxsa[PRE_MAX];
    __shared__ int    idxs[PRE_MAX];              // original index, sorted order
    __shared__ float4 keptb4[TOP_K];
    __shared__ float  kepta[TOP_K];
    __shared__ int keep_sh[TOP_K];
    __shared__ unsigned sh_cnt;
    __shared__ int sh_kept;

    const int tid  = threadIdx.x;
    const int lane = tid & 63;
    const int wid  = tid >> 6;

    // ---- issue all global loads first ----
    const float4* conf4 = reinterpret_cast<const float4*>(conf);
    const float4* iou4  = reinterpret_cast<const float4*>(iou);
    float4 cf[8], io[4];
    #pragma unroll
    for (int m = 0; m < 2; ++m)
        #pragma unroll
        for (int q = 0; q < 4; ++q)
            cf[m * 4 + q] = conf4[(m * NT + tid) * 4 + q];
    #pragma unroll
    for (int m = 0; m < 2; ++m)
        #pragma unroll
        for (int r = 0; r < 2; ++r)
            io[m * 2 + r] = iou4[(m * NT + tid) * 2 + r];

    // ---- zero own histogram copy (wave-private) ----
    #pragma unroll
    for (int i = 0; i < 4; ++i) hist[wid][lane + 64 * i] = 0;
    if (tid == 0) { sh_cnt = 0; sh_kept = 0; }
    __asm__ volatile("s_waitcnt lgkmcnt(0)" ::: "memory");

    // ---- Phase 1: scores (registers) + SUBSAMPLED per-wave histogram ----
    // Histogram built from every 4th box (q==0,4): 2048 atomics total instead
    // of 8192. Threshold choice only affects C's size, never correctness.
    unsigned sbv[BPT];
    #pragma unroll
    for (int m = 0; m < 2; ++m) {
        float sc[8], uu[8];
        #pragma unroll
        for (int q = 0; q < 4; ++q) {
            sc[2 * q]     = cf[m * 4 + q].y;
            sc[2 * q + 1] = cf[m * 4 + q].w;
        }
        #pragma unroll
        for (int r = 0; r < 2; ++r) {
            uu[4 * r + 0] = io[m * 2 + r].x; uu[4 * r + 1] = io[m * 2 + r].y;
            uu[4 * r + 2] = io[m * 2 + r].z; uu[4 * r + 3] = io[m * 2 + r].w;
        }
        #pragma unroll
        for (int q = 0; q < 8; ++q) {
            float u = fminf(fmaxf(uu[q], 0.0f), 1.0f);
            float s = sqrtf(sc[q] * u);
            unsigned sb = __float_as_uint(s);   // s >= 0 -> monotonic bits
            sbv[m * 8 + q] = sb;
            if ((q & 3) == 0) {                 // subsample: idx % 4 == 0
                int bin = (int)(s * 256.0f); bin = bin > 255 ? 255 : bin;
                atomicAdd(&hist[wid][bin], 1u);
            }
        }
    }
    __syncthreads();                              // B1

    // ---- Phase 2: threshold bin B (wave-redundant, deterministic) ----
    int B;
    {
        unsigned c0 = 0, c1 = 0, c2 = 0, c3 = 0;
        #pragma unroll
        for (int w = 0; w < NWAVE; ++w) {
            uint4 h = *(const uint4*)&hist[w][4 * lane];
            c0 += h.x; c1 += h.y; c2 += h.z; c3 += h.w;
        }
        find_thresh(c0, c1, c2, c3, lane, MSEL_SUB, B);
    }

    // ---- Phase 3: compact (one aggregated atomic per wave per q-step) ----
    #pragma unroll
    for (int m = 0; m < 2; ++m) {
        #pragma unroll
        for (int q = 0; q < 8; ++q) {
            unsigned sb = sbv[m * 8 + q];
            float s = __uint_as_float(sb);
            int bin = (int)(s * 256.0f); bin = bin > 255 ? 255 : bin;
            bool pred = (bin >= B);
            unsigned long long bal = __ballot(pred);
            if (pred) {
                int myoff = __popcll(bal & ((1ull << lane) - 1ull));
                unsigned base = 0;
                if (myoff == 0) base = atomicAdd(&sh_cnt, (unsigned)__popcll(bal));
                base = (unsigned)__builtin_amdgcn_readfirstlane((int)base);
                unsigned pos = base + (unsigned)myoff;
                if (pos < PRE_MAX)
                    cand[pos] = ((unsigned long long)(~sb) << 32)
                              | (unsigned)((m * NT + tid) * 8 + q);
            }
        }
    }
    __syncthreads();                              // B2
    const int C = (int)sh_cnt;

    bool main_ok = (C <= PRE_MAX);
    if (main_ok) {
        // ---- Phase 4: rank sort (exact; keys unique) + parallel box decode ----
        if (tid < C) {
            unsigned long long k = cand[tid];
            int r = 0, j = 0;
            for (; j + 4 <= C; j += 4) {
                r += (cand[j]     < k) ? 1 : 0;
                r += (cand[j + 1] < k) ? 1 : 0;
                r += (cand[j + 2] < k) ? 1 : 0;
                r += (cand[j + 3] < k) ? 1 : 0;
            }
            for (; j < C; ++j) r += (cand[j] < k) ? 1 : 0;
            int cidx = (int)(k & 0xFFFFFFFFull);
            float x1, y1, x2, y2, area;
            decode_box(cidx, loc, priors, x1, y1, x2, y2, area);
            boxs4[r] = make_float4(x1, y1, x2, y2);
            boxsa[r] = area;
            idxs[r] = cidx;
        }
        __syncthreads();                          // B3

        // ---- Phase 5: batch-mask greedy NMS (2 barriers per batch) ----
        int kept_reg = 0;                         // accurate in wave 0 only
        for (int p = 0; p < C; p += 64) {
            unsigned long long sup_prev = 0ull;   // wave-0 register, crosses B4
            // stage A (wave 0): batch vs previously-kept boxes
            if (tid < 64) {
                int pos = p + lane;
                bool valid = pos < C;
                int rp = valid ? pos : 0;
                float4 b = boxs4[rp]; float a = boxsa[rp];
                bool supP = !valid;
                for (int j = 0; j < kept_reg; ++j) {
                    float4 kb = keptb4[j]; float ka = kepta[j];
                    float iw = fmaxf(fminf(b.z, kb.z) - fmaxf(b.x, kb.x), 0.f);
                    float ih = fmaxf(fminf(b.w, kb.w) - fmaxf(b.y, kb.y), 0.f);
                    float inter = iw * ih;
                    supP = supP || (inter > IOU_THR * (a + ka - inter));
                }
                sup_prev = __ballot(supP);
            }
            // stage B (all 512 threads): 64x64 IoU bit-matrix, 8 pairs each
            {
                int r  = tid >> 3;
                int cb = tid & 7;
                int rp = (p + r < C) ? p + r : 0;
                float4 rb = boxs4[rp]; float ra = boxsa[rp];
                unsigned byte = 0;
                #pragma unroll
                for (int k = 0; k < 8; ++k) {
                    int c = cb * 8 + k;
                    int cp = (p + c < C) ? p + c : 0;
                    float4 cx = boxs4[cp]; float ca = boxsa[cp];
                    float iw = fmaxf(fminf(rb.z, cx.z) - fmaxf(rb.x, cx.x), 0.f);
                    float ih = fmaxf(fminf(rb.w, cx.w) - fmaxf(rb.y, cx.y), 0.f);
                    float inter = iw * ih;
                    byte |= (unsigned)((inter > IOU_THR * (ra + ca - inter)) ? 1u : 0u) << k;
                }
                ((unsigned char*)maskbuf)[tid] = (unsigned char)byte;
            }
            __syncthreads();                      // B4 (per batch)

            // stage C (wave 0): exact greedy recurrence — scalar via readlane
            if (tid < 64) {
                unsigned long long myrow = maskbuf[lane];
                unsigned mlo = (unsigned)myrow;
                unsigned mhi = (unsigned)(myrow >> 32);
                unsigned long long keepcur = 0ull;
                const int kept0 = kept_reg;
                int kept = kept0;
                for (int j = 0; j < 64 && kept < TOP_K; ++j) {
                    if (!((sup_prev >> j) & 1ull)) {
                        unsigned long long mj =
                            ((unsigned long long)(unsigned)__builtin_amdgcn_readlane((int)mhi, j) << 32)
                          | (unsigned)__builtin_amdgcn_readlane((int)mlo, j);
                        unsigned long long lower = (1ull << j) - 1ull;
                        if (!(mj & keepcur & lower)) { keepcur |= 1ull << j; ++kept; }
                    }
                }
                unsigned long long lowm = (1ull << lane) - 1ull;
                if ((keepcur >> lane) & 1ull) {
                    int rank = kept0 + __popcll(keepcur & lowm);
                    int pos = p + lane;
                    keep_sh[rank] = idxs[pos];
                    keptb4[rank] = boxs4[pos];
                    kepta[rank] = boxsa[pos];
                }
                kept_reg = kept;
                if (lane == 0) sh_kept = kept;
            }
            __syncthreads();                      // B5 (per batch)
            if (sh_kept >= TOP_K) break;
        }
    }
    // sh_kept last written before B5; uniform view here.
    const int kept_total = main_ok ? sh_kept : 0;
    const bool need_fallback = (kept_total < TOP_K);

    // ---- Fallback: exact full path (never taken on this data) ----
    if (need_fallback) {
        #pragma unroll
        for (int m = 0; m < 2; ++m) {
            #pragma unroll
            for (int q = 0; q < 8; ++q) {
                int i = (m * NT + tid) * 8 + q;
                keys[i] = ((unsigned long long)(~sbv[m * 8 + q]) << 32) | (unsigned)i;
            }
        }
        __syncthreads();
        bitonic_sort(keys, NBOX, tid);
        if (tid < 64) greedy_nms_serial(keys, NBOX, tid, loc, priors, keep_sh);
        __syncthreads();
    }
    const int kcnt = need_fallback ? TOP_K : kept_total;

    // ---- Phase 6: output rows (tid 0..49 = wave 0; no extra barrier) ----
    if (tid < TOP_K) {
        int src = (tid < kcnt) ? tid : 0;   // fill = first kept index
        int i = keep_sh[src];
        float4 pr = *reinterpret_cast<const float4*>(priors + 4 * i);
        float cx = pr.x + loc[i * 14 + 0] * VAR0 * pr.z;
        float cy = pr.y + loc[i * 14 + 1] * VAR0 * pr.w;
        float hw = pr.z * expf(loc[i * 14 + 2] * VAR0) * 0.5f;
        float hh = pr.w * expf(loc[i * 14 + 3] * VAR1) * 0.5f;
        float* o = out + tid * 15;
        o[0] = cx - hw;
        o[1] = cy - hh;
        o[2] = cx + hw;
        o[3] = cy + hh;
        #pragma unroll
        for (int q = 0; q < 5; ++q) {
            o[4 + 2 * q] = pr.x + loc[i * 14 + 4 + 2 * q] * VAR0 * pr.z;
            o[5 + 2 * q] = pr.y + loc[i * 14 + 5 + 2 * q] * VAR0 * pr.w;
        }
        float cc = conf[i * 2 + 1];
        float u  = fminf(fmaxf(iou[i], 0.0f), 1.0f);
        o[14] = sqrtf(cc * u);
    }
}

extern "C" void kernel_launch(void* const* d_in, const int* in_sizes, int n_in,
                              void* d_out, int out_size, void* d_ws, size_t ws_size,
                              hipStream_t stream) {
    const float* loc    = (const float*)d_in[0];
    const float* conf   = (const float*)d_in[1];
    const float* iou    = (const float*)d_in[2];
    const float* priors = (const float*)d_in[3];
    float* out = (float*)d_out;

    yunet_fused_kernel<<<1, NT, 0, stream>>>(loc, conf, iou, priors, out);
}